// Round 10
// baseline (173.795 us; speedup 1.0000x reference)
//
#include <hip/hip_runtime.h>

typedef short bf16x8 __attribute__((ext_vector_type(8)));
typedef unsigned short u16x8 __attribute__((ext_vector_type(8)));
typedef float f32x4 __attribute__((ext_vector_type(4)));
typedef float f32x16 __attribute__((ext_vector_type(16)));
typedef unsigned int u32x2 __attribute__((ext_vector_type(2)));

#define LOG2E 1.44269504088896340736f

__device__ __forceinline__ float bf2f(unsigned short u) {
  union { unsigned int i; float f; } v; v.i = ((unsigned int)u) << 16; return v.f;
}
__device__ __forceinline__ unsigned short f2bf(float f) {
  union { float fl; unsigned int i; } v; v.fl = f;
  unsigned int r = v.i + 0x7FFFu + ((v.i >> 16) & 1u);
  return (unsigned short)(r >> 16);
}
__device__ __forceinline__ unsigned int cvt_pk_bf16(float lo, float hi) {
  unsigned int d;
  asm("v_cvt_pk_bf16_f32 %0, %1, %2" : "=v"(d) : "v"(lo), "v"(hi));
  return d;
}
__device__ __forceinline__ void perm_swap(unsigned int& a, unsigned int& b) {
  asm("v_permlane32_swap_b32 %0, %1" : "+v"(a), "+v"(b));
}
__device__ __forceinline__ bf16x8 mk8(unsigned int a, unsigned int b,
                                      unsigned int c, unsigned int d) {
  union { unsigned int u[4]; bf16x8 v; } r;
  r.u[0] = a; r.u[1] = b; r.u[2] = c; r.u[3] = d;
  return r.v;
}
__device__ __forceinline__ void gload_lds16(const void* g, void* l) {
  __builtin_amdgcn_global_load_lds(
      (const __attribute__((address_space(1))) void*)g,
      (__attribute__((address_space(3))) void*)l, 16, 0, 0);
}

// ---------------- fused fp32 -> bf16 conversions (x, W_qkv, W_proj) ----------------
__global__ __launch_bounds__(256) void cvt_all(const float* __restrict__ x,
                                               const float* __restrict__ wqkv,
                                               const float* __restrict__ wproj,
                                               unsigned short* __restrict__ xb,
                                               unsigned short* __restrict__ wqb,
                                               unsigned short* __restrict__ wpb) {
  int i = blockIdx.x * 256 + threadIdx.x;  // 1,048,576 total (x8 units)
  const float* src; unsigned short* dst; int off;
  if (i < 524288)       { src = x;     dst = xb;  off = i; }
  else if (i < 917504)  { src = wqkv;  dst = wqb; off = i - 524288; }
  else                  { src = wproj; dst = wpb; off = i - 917504; }
  float4 a = ((const float4*)src)[2 * off];
  float4 b = ((const float4*)src)[2 * off + 1];
  u16x8 o;
  o[0] = f2bf(a.x); o[1] = f2bf(a.y); o[2] = f2bf(a.z); o[3] = f2bf(a.w);
  o[4] = f2bf(b.x); o[5] = f2bf(b.y); o[6] = f2bf(b.z); o[7] = f2bf(b.w);
  ((u16x8*)dst)[off] = o;
}

// ---------------- bias -> frag-linear DMA-ordered layout ----------------
// Slice (qt,kb) is 16 KB contiguous: chunk = ((qt*32+kb)*4 + w)*256 + c*64 + l.
// Value = bias[q][k]*log2e, q = qt*128+w*32+(l&31),
// k = kb*64 + kg*32 + (r&3)+8*(r>>2)+4*(l>>5), m = kg*16+r = c*8+e.
__global__ __launch_bounds__(256) void prep_bias(const float* __restrict__ bias,
                                                 unsigned short* __restrict__ biasArr) {
  int tid = blockIdx.x * 256 + threadIdx.x;  // 262,144 = (qt,kb,w,l,kg)
  int kg = tid & 1;
  int l = (tid >> 1) & 63;
  int w = (tid >> 7) & 3;
  int kb = (tid >> 9) & 31;
  int qt = (tid >> 14) & 15;
  int q = qt * 128 + w * 32 + (l & 31);
  int kbase = kb * 64 + kg * 32 + (l >> 5) * 4;
  const float* src = bias + (size_t)q * 2048 + kbase;
  u16x8 oa, ob;
#pragma unroll
  for (int rr = 0; rr < 4; ++rr) {
    float4 g = *(const float4*)(src + rr * 8);
    unsigned short e0 = f2bf(g.x * LOG2E), e1 = f2bf(g.y * LOG2E);
    unsigned short e2 = f2bf(g.z * LOG2E), e3 = f2bf(g.w * LOG2E);
    if (rr < 2) {
      oa[rr * 4 + 0] = e0; oa[rr * 4 + 1] = e1; oa[rr * 4 + 2] = e2; oa[rr * 4 + 3] = e3;
    } else {
      ob[(rr - 2) * 4 + 0] = e0; ob[(rr - 2) * 4 + 1] = e1;
      ob[(rr - 2) * 4 + 2] = e2; ob[(rr - 2) * 4 + 3] = e3;
    }
  }
  int base = (((qt * 32 + kb) * 4 + w) * 4 + kg * 2) * 64 + l;
  ((u16x8*)biasArr)[base] = oa;
  ((u16x8*)biasArr)[base + 64] = ob;
}

// ---------------- GEMM NT: out[m][n] = sum_k A[m][k]*B[n][k] ----------------
template <bool F32OUT>
__global__ __launch_bounds__(256) void gemm_nt(const unsigned short* __restrict__ A,
                                               const unsigned short* __restrict__ B,
                                               void* __restrict__ Cout,
                                               const float* __restrict__ bias,
                                               int M, int N, int K) {
  __shared__ __align__(16) unsigned short a_lds[128 * 64];
  __shared__ __align__(16) unsigned short b_lds[128 * 64];
  const int t = threadIdx.x;
  const int lane = t & 63, w = t >> 6;
  const int wm = w >> 1, wn = w & 1;
  const int r16 = lane >> 4, c16 = lane & 15;
  const int m0 = blockIdx.y * 128, n0 = blockIdx.x * 128;
  f32x4 acc[4][4] = {};
  for (int k0 = 0; k0 < K; k0 += 64) {
#pragma unroll
    for (int i = 0; i < 4; ++i) {
      int s = i * 256 + t;
      int row = s >> 3, c = s & 7;
      int cs = c ^ (row & 7);
      gload_lds16(A + (size_t)(m0 + row) * K + k0 + cs * 8, (char*)a_lds + s * 16);
      gload_lds16(B + (size_t)(n0 + row) * K + k0 + cs * 8, (char*)b_lds + s * 16);
    }
    __syncthreads();
#pragma unroll
    for (int ks = 0; ks < 2; ++ks) {
      bf16x8 af[4], bfr[4];
#pragma unroll
      for (int mi = 0; mi < 4; ++mi) {
        int row = wm * 64 + mi * 16 + c16;
        int ch = (r16 + ks * 4) ^ (row & 7);
        af[mi] = *(const bf16x8*)&a_lds[row * 64 + ch * 8];
      }
#pragma unroll
      for (int ni = 0; ni < 4; ++ni) {
        int row = wn * 64 + ni * 16 + c16;
        int ch = (r16 + ks * 4) ^ (row & 7);
        bfr[ni] = *(const bf16x8*)&b_lds[row * 64 + ch * 8];
      }
#pragma unroll
      for (int mi = 0; mi < 4; ++mi)
#pragma unroll
        for (int ni = 0; ni < 4; ++ni)
          acc[mi][ni] = __builtin_amdgcn_mfma_f32_16x16x32_bf16(af[mi], bfr[ni], acc[mi][ni], 0, 0, 0);
    }
    __syncthreads();
  }
#pragma unroll
  for (int mi = 0; mi < 4; ++mi)
#pragma unroll
    for (int ni = 0; ni < 4; ++ni)
#pragma unroll
      for (int r = 0; r < 4; ++r) {
        int m = m0 + wm * 64 + mi * 16 + r16 * 4 + r;
        int n = n0 + wn * 64 + ni * 16 + c16;
        float v = acc[mi][ni][r];
        if constexpr (F32OUT) {
          ((float*)Cout)[(size_t)m * N + n] = v + bias[n];
        } else {
          ((unsigned short*)Cout)[(size_t)m * N + n] = f2bf(v);
        }
      }
}

// ---------------- normalize + bias + pack q,k,(v transposed) ----------------
__global__ __launch_bounds__(256) void norm_pack(const unsigned short* __restrict__ pre,
                                                 const float* __restrict__ q_bias,
                                                 const float* __restrict__ v_bias,
                                                 const float* __restrict__ scale_mul,
                                                 unsigned short* __restrict__ qo,
                                                 unsigned short* __restrict__ ko,
                                                 unsigned short* __restrict__ vto) {
  __shared__ float tl[64][65];
  const int t = threadIdx.x;
  const int li = t >> 2, dq = t & 3;
  const int tile = blockIdx.x;  // b*32 + lt
  const int sl = blockIdx.y;    // qkv*16 + h
  const int qkv = sl >> 4, h = sl & 15;
  const int b = tile >> 5, lt = tile & 31;
  const int l = lt * 64 + li;
  const int dbase = dq * 16;
  const unsigned short* src = pre + ((size_t)b * 2048 + l) * 3072 + qkv * 1024 + h * 64 + dbase;
  float v[16];
  bf16x8 x0 = *(const bf16x8*)src;
  bf16x8 x1 = *(const bf16x8*)(src + 8);
#pragma unroll
  for (int j = 0; j < 8; ++j) {
    v[j] = bf2f((unsigned short)x0[j]);
    v[8 + j] = bf2f((unsigned short)x1[j]);
  }
  if (qkv == 0) {
#pragma unroll
    for (int j = 0; j < 16; ++j) v[j] += q_bias[h * 64 + dbase + j];
  } else if (qkv == 2) {
#pragma unroll
    for (int j = 0; j < 16; ++j) v[j] += v_bias[h * 64 + dbase + j];
  }
  if (qkv < 2) {
    float ss = 0.f;
#pragma unroll
    for (int j = 0; j < 16; ++j) ss += v[j] * v[j];
    ss += __shfl_xor(ss, 1);
    ss += __shfl_xor(ss, 2);
    float inv = 1.0f / fmaxf(sqrtf(ss), 1e-12f);
    if (qkv == 0) inv *= __expf(fminf(scale_mul[h], 4.6051701859880914f));
    u16x8 o0, o1;
#pragma unroll
    for (int j = 0; j < 8; ++j) {
      o0[j] = f2bf(v[j] * inv);
      o1[j] = f2bf(v[8 + j] * inv);
    }
    unsigned short* dst = (qkv == 0 ? qo : ko) + ((size_t)(b * 16 + h) * 2048 + l) * 64 + dbase;
    *(u16x8*)dst = o0;
    *(u16x8*)(dst + 8) = o1;
  } else {
#pragma unroll
    for (int j = 0; j < 16; ++j) tl[li][dbase + j] = v[j];
    __syncthreads();
    const int d = li;
    const int lb = dq * 16;
    u16x8 o0, o1;
#pragma unroll
    for (int j = 0; j < 8; ++j) {
      o0[j] = f2bf(tl[lb + j][d]);
      o1[j] = f2bf(tl[lb + 8 + j][d]);
    }
    unsigned short* dst = vto + ((size_t)(b * 16 + h) * 64 + d) * 2048 + lt * 64 + lb;
    *(u16x8*)dst = o0;
    *(u16x8*)(dst + 8) = o1;
  }
}

// ---------------- flash attention: 32x32 MFMA, in-block K-split x2 ----------------
// 8 waves/block (512 thr): waves 0-3 (sp=0) process k in [0,1024), waves 4-7
// (sp=1) k in [1024,2048), SAME 128 q-rows. Fixed-shift softmax => (O,lsum)
// partials additive; sp=1 dumps partials to LDS (reusing bias buffers), one
// barrier, sp=0 adds + normalizes + writes. Doubles waves/SIMD (2->4) with
// zero extra HBM traffic. Inner iteration identical to R9.
__global__ __launch_bounds__(512) void attn_fwd(const unsigned short* __restrict__ qb,
                                                const unsigned short* __restrict__ kbuf,
                                                const unsigned short* __restrict__ vtb,
                                                const unsigned short* __restrict__ biasArr,
                                                unsigned short* __restrict__ oup) {
  __shared__ __align__(16) unsigned short k_lds[2][4096];   // 2 x  8 KB
  __shared__ __align__(16) unsigned short vt_lds[2][4096];  // 2 x  8 KB
  __shared__ __align__(16) unsigned short b_lds[2][8192];   // 2 x 16 KB
  const int t = threadIdx.x;
  const int lane = t & 63, w = t >> 6;
  const int sp = w >> 2;        // k-split half
  const int wq = w & 3;         // q sub-block within the half
  const int tt = t & 255;       // thread id within the half (4 waves)
  const int l31 = lane & 31, hi = lane >> 5;
  const int bid = blockIdx.x;
  const int swz = (bid & 7) * 64 + (bid >> 3);
  const int bh = swz >> 4;
  const int qt = swz & 15;
  const int q0 = qt * 128;
  const int h = bh & 15;
  const size_t base = (size_t)bh * 2048 * 64;
  // staging sources (pre-permuted global, linear LDS dest) — per half
  const unsigned short* kp = kbuf + base + (size_t)(tt & 31) * 64 +
                             ((tt >> 6) & 3) * 16 + ((tt >> 5) & 1) * 8;
  const unsigned short* vp = vtb + base + (size_t)(tt & 31) * 2048 +
                             ((tt >> 6) & 3) * 16 + ((tt >> 5) & 1) * 8;
  const unsigned short* bsrc = biasArr + (size_t)qt * 262144 + tt * 8;
  // Q fragments (B-operand) — both halves load the same q-rows
  bf16x8 qf[4];
  {
    const unsigned short* qp = qb + base + (size_t)(q0 + wq * 32 + l31) * 64 + hi * 8;
    qf[0] = *(const bf16x8*)qp;
    qf[1] = *(const bf16x8*)(qp + 16);
    qf[2] = *(const bf16x8*)(qp + 32);
    qf[3] = *(const bf16x8*)(qp + 48);
  }
  f32x16 o0 = {}, o1 = {};
  float ls0 = 0.f, ls1 = 0.f;
  const unsigned short* bl = b_lds[sp] + wq * 2048 + lane * 8;  // + c*512

  for (int kbl = 0; kbl < 16; ++kbl) {
    const int kb = sp * 16 + kbl;
    // stage K (2), V^T (2), bias (4) into this half's frag-linear LDS
    gload_lds16(kp + (size_t)kb * 4096, (char*)k_lds[sp] + tt * 16);
    gload_lds16(kp + (size_t)kb * 4096 + 2048, (char*)k_lds[sp] + tt * 16 + 4096);
    gload_lds16(vp + kb * 64, (char*)vt_lds[sp] + tt * 16);
    gload_lds16(vp + kb * 64 + 32 * 2048, (char*)vt_lds[sp] + tt * 16 + 4096);
#pragma unroll
    for (int i = 0; i < 4; ++i)
      gload_lds16(bsrc + kb * 8192 + i * 2048, (char*)b_lds[sp] + tt * 16 + i * 4096);
    __syncthreads();
    // S^T = K Q^T
    f32x16 s0 = {}, s1 = {};
    __builtin_amdgcn_s_setprio(1);
#pragma unroll
    for (int dc = 0; dc < 4; ++dc) {
      bf16x8 kf0 = *(const bf16x8*)&k_lds[sp][dc * 512 + lane * 8];
      bf16x8 kf1 = *(const bf16x8*)&k_lds[sp][(4 + dc) * 512 + lane * 8];
      s0 = __builtin_amdgcn_mfma_f32_32x32x16_bf16(kf0, qf[dc], s0, 0, 0, 0);
      s1 = __builtin_amdgcn_mfma_f32_32x32x16_bf16(kf1, qf[dc], s1, 0, 0, 0);
    }
    __builtin_amdgcn_s_setprio(0);
    // bias from LDS, p = exp2(S*log2e + bias')
    bf16x8 b0 = *(const bf16x8*)(bl);
    bf16x8 b1 = *(const bf16x8*)(bl + 512);
    bf16x8 b2 = *(const bf16x8*)(bl + 1024);
    bf16x8 b3 = *(const bf16x8*)(bl + 1536);
    float p0[16], p1[16];
#pragma unroll
    for (int r = 0; r < 8; ++r) {
      p0[r] = __builtin_amdgcn_exp2f(__builtin_fmaf(s0[r], LOG2E, bf2f((unsigned short)b0[r])));
      p0[8 + r] = __builtin_amdgcn_exp2f(__builtin_fmaf(s0[8 + r], LOG2E, bf2f((unsigned short)b1[r])));
      p1[r] = __builtin_amdgcn_exp2f(__builtin_fmaf(s1[r], LOG2E, bf2f((unsigned short)b2[r])));
      p1[8 + r] = __builtin_amdgcn_exp2f(__builtin_fmaf(s1[8 + r], LOG2E, bf2f((unsigned short)b3[r])));
    }
#pragma unroll
    for (int r = 0; r < 16; ++r) { ls0 += p0[r]; ls1 += p1[r]; }
    // P -> PV B-frags in-register (cvt_pk + permlane32_swap)
    unsigned int x0 = cvt_pk_bf16(p0[0], p0[1]), x1 = cvt_pk_bf16(p0[2], p0[3]);
    unsigned int y0 = cvt_pk_bf16(p0[4], p0[5]), y1 = cvt_pk_bf16(p0[6], p0[7]);
    unsigned int z0 = cvt_pk_bf16(p0[8], p0[9]), z1 = cvt_pk_bf16(p0[10], p0[11]);
    unsigned int w0 = cvt_pk_bf16(p0[12], p0[13]), w1 = cvt_pk_bf16(p0[14], p0[15]);
    perm_swap(x0, y0); perm_swap(x1, y1); perm_swap(z0, w0); perm_swap(z1, w1);
    bf16x8 pf0 = mk8(x0, x1, y0, y1);
    bf16x8 pf1 = mk8(z0, z1, w0, w1);
    unsigned int a0 = cvt_pk_bf16(p1[0], p1[1]), a1 = cvt_pk_bf16(p1[2], p1[3]);
    unsigned int c0 = cvt_pk_bf16(p1[4], p1[5]), c1 = cvt_pk_bf16(p1[6], p1[7]);
    unsigned int d0 = cvt_pk_bf16(p1[8], p1[9]), d1 = cvt_pk_bf16(p1[10], p1[11]);
    unsigned int e0 = cvt_pk_bf16(p1[12], p1[13]), e1 = cvt_pk_bf16(p1[14], p1[15]);
    perm_swap(a0, c0); perm_swap(a1, c1); perm_swap(d0, e0); perm_swap(d1, e1);
    bf16x8 pf2 = mk8(a0, a1, c0, c1);
    bf16x8 pf3 = mk8(d0, d1, e0, e1);
    // O^T += V^T P^T
    bf16x8 pf[4] = {pf0, pf1, pf2, pf3};
    __builtin_amdgcn_s_setprio(1);
#pragma unroll
    for (int kc = 0; kc < 4; ++kc) {
      bf16x8 vf0 = *(const bf16x8*)&vt_lds[sp][kc * 512 + lane * 8];
      bf16x8 vf1 = *(const bf16x8*)&vt_lds[sp][(4 + kc) * 512 + lane * 8];
      o0 = __builtin_amdgcn_mfma_f32_32x32x16_bf16(vf0, pf[kc], o0, 0, 0, 0);
      o1 = __builtin_amdgcn_mfma_f32_32x32x16_bf16(vf1, pf[kc], o1, 0, 0, 0);
    }
    __builtin_amdgcn_s_setprio(0);
    __syncthreads();
  }
  // combine: sp=1 dumps partials into LDS (overlaying b_lds/k_lds), sp=0 adds.
  {
    float* fO = (float*)b_lds;        // 32 KB: [wq*64+lane]*32 + i
    float* fL = (float*)k_lds;        //  2 KB: [wq*64+lane]*2 + {0,1}
    const int idx = (wq * 64 + lane) * 32;
    if (sp == 1) {
#pragma unroll
      for (int i = 0; i < 16; ++i) { fO[idx + i] = o0[i]; fO[idx + 16 + i] = o1[i]; }
      fL[(wq * 64 + lane) * 2] = ls0;
      fL[(wq * 64 + lane) * 2 + 1] = ls1;
    }
    __syncthreads();
    if (sp == 0) {
#pragma unroll
      for (int i = 0; i < 16; ++i) { o0[i] += fO[idx + i]; o1[i] += fO[idx + 16 + i]; }
      ls0 += fL[(wq * 64 + lane) * 2];
      ls1 += fL[(wq * 64 + lane) * 2 + 1];
      float lsum = ls0 + ls1;
      lsum += __shfl_xor(lsum, 32);
      float inv = 1.0f / lsum;
      const int b = bh >> 4;
      unsigned short* orow = oup + ((size_t)b * 2048 + q0 + wq * 32 + l31) * 1024 + h * 64;
#pragma unroll
      for (int dg = 0; dg < 2; ++dg) {
#pragma unroll
        for (int rr = 0; rr < 4; ++rr) {
          float v0 = (dg ? o1[rr * 4 + 0] : o0[rr * 4 + 0]) * inv;
          float v1 = (dg ? o1[rr * 4 + 1] : o0[rr * 4 + 1]) * inv;
          float v2 = (dg ? o1[rr * 4 + 2] : o0[rr * 4 + 2]) * inv;
          float v3 = (dg ? o1[rr * 4 + 3] : o0[rr * 4 + 3]) * inv;
          u32x2 pk2;
          pk2[0] = cvt_pk_bf16(v0, v1);
          pk2[1] = cvt_pk_bf16(v2, v3);
          int d = dg * 32 + rr * 8 + hi * 4;
          *(u32x2*)(orow + d) = pk2;
        }
      }
    }
  }
}

extern "C" void kernel_launch(void* const* d_in, const int* in_sizes, int n_in,
                              void* d_out, int out_size, void* d_ws, size_t ws_size,
                              hipStream_t stream) {
  const float* x = (const float*)d_in[0];
  const float* attn_bias = (const float*)d_in[1];
  const float* W_qkv = (const float*)d_in[2];
  const float* q_bias = (const float*)d_in[3];
  const float* v_bias = (const float*)d_in[4];
  const float* scale_mul = (const float*)d_in[5];
  const float* W_proj = (const float*)d_in[6];
  const float* b_proj = (const float*)d_in[7];
  float* out = (float*)d_out;
  char* ws = (char*)d_ws;

  unsigned short* x_bf = (unsigned short*)(ws + 0);            //  8 MB
  unsigned short* wqkv_bf = (unsigned short*)(ws + 8388608);   //  6 MB
  unsigned short* wproj_bf = (unsigned short*)(ws + 14680064); //  2 MB
  unsigned short* biasArr = (unsigned short*)(ws + 16777216);  //  8 MB (DMA-ordered, *log2e)
  unsigned short* q_pk = (unsigned short*)(ws + 25165824);     //  8 MB
  unsigned short* k_pk = (unsigned short*)(ws + 33554432);     //  8 MB
  unsigned short* vt_pk = (unsigned short*)(ws + 41943040);    //  8 MB
  unsigned short* oup_bf = (unsigned short*)(ws + 50331648);   //  8 MB
  unsigned short* pre_qkv = (unsigned short*)(ws + 58720256);  // 24 MB

  cvt_all<<<4096, 256, 0, stream>>>(x, W_qkv, W_proj, x_bf, wqkv_bf, wproj_bf);
  prep_bias<<<1024, 256, 0, stream>>>(attn_bias, biasArr);
  gemm_nt<false><<<dim3(24, 32), 256, 0, stream>>>(x_bf, wqkv_bf, (void*)pre_qkv, nullptr,
                                                   4096, 3072, 1024);
  norm_pack<<<dim3(64, 48), 256, 0, stream>>>(pre_qkv, q_bias, v_bias, scale_mul,
                                              q_pk, k_pk, vt_pk);
  attn_fwd<<<512, 512, 0, stream>>>(q_pk, k_pk, vt_pk, biasArr, oup_bf);
  gemm_nt<true><<<dim3(8, 32), 256, 0, stream>>>(oup_bf, wproj_bf, (void*)out, b_proj,
                                                 4096, 1024, 1024);
}

// Round 11
// 152.504 us; speedup vs baseline: 1.1396x; 1.1396x over previous
//
#include <hip/hip_runtime.h>

typedef short bf16x8 __attribute__((ext_vector_type(8)));
typedef unsigned short u16x8 __attribute__((ext_vector_type(8)));
typedef float f32x4 __attribute__((ext_vector_type(4)));
typedef float f32x16 __attribute__((ext_vector_type(16)));
typedef unsigned int u32x2 __attribute__((ext_vector_type(2)));

#define LOG2E 1.44269504088896340736f

__device__ __forceinline__ float bf2f(unsigned short u) {
  union { unsigned int i; float f; } v; v.i = ((unsigned int)u) << 16; return v.f;
}
__device__ __forceinline__ unsigned short f2bf(float f) {
  union { float fl; unsigned int i; } v; v.fl = f;
  unsigned int r = v.i + 0x7FFFu + ((v.i >> 16) & 1u);
  return (unsigned short)(r >> 16);
}
__device__ __forceinline__ unsigned int cvt_pk_bf16(float lo, float hi) {
  unsigned int d;
  asm("v_cvt_pk_bf16_f32 %0, %1, %2" : "=v"(d) : "v"(lo), "v"(hi));
  return d;
}
__device__ __forceinline__ void perm_swap(unsigned int& a, unsigned int& b) {
  asm("v_permlane32_swap_b32 %0, %1" : "+v"(a), "+v"(b));
}
__device__ __forceinline__ bf16x8 mk8(unsigned int a, unsigned int b,
                                      unsigned int c, unsigned int d) {
  union { unsigned int u[4]; bf16x8 v; } r;
  r.u[0] = a; r.u[1] = b; r.u[2] = c; r.u[3] = d;
  return r.v;
}
__device__ __forceinline__ void gload_lds16(const void* g, void* l) {
  __builtin_amdgcn_global_load_lds(
      (const __attribute__((address_space(1))) void*)g,
      (__attribute__((address_space(3))) void*)l, 16, 0, 0);
}

// ---------------- fused fp32 -> bf16 conversions (x, W_qkv, W_proj) ----------------
__global__ __launch_bounds__(256) void cvt_all(const float* __restrict__ x,
                                               const float* __restrict__ wqkv,
                                               const float* __restrict__ wproj,
                                               unsigned short* __restrict__ xb,
                                               unsigned short* __restrict__ wqb,
                                               unsigned short* __restrict__ wpb) {
  int i = blockIdx.x * 256 + threadIdx.x;  // 1,048,576 total (x8 units)
  const float* src; unsigned short* dst; int off;
  if (i < 524288)       { src = x;     dst = xb;  off = i; }
  else if (i < 917504)  { src = wqkv;  dst = wqb; off = i - 524288; }
  else                  { src = wproj; dst = wpb; off = i - 917504; }
  float4 a = ((const float4*)src)[2 * off];
  float4 b = ((const float4*)src)[2 * off + 1];
  u16x8 o;
  o[0] = f2bf(a.x); o[1] = f2bf(a.y); o[2] = f2bf(a.z); o[3] = f2bf(a.w);
  o[4] = f2bf(b.x); o[5] = f2bf(b.y); o[6] = f2bf(b.z); o[7] = f2bf(b.w);
  ((u16x8*)dst)[off] = o;
}

// ---------------- bias -> frag-linear DMA-ordered layout ----------------
__global__ __launch_bounds__(256) void prep_bias(const float* __restrict__ bias,
                                                 unsigned short* __restrict__ biasArr) {
  int tid = blockIdx.x * 256 + threadIdx.x;  // 262,144 = (qt,kb,w,l,kg)
  int kg = tid & 1;
  int l = (tid >> 1) & 63;
  int w = (tid >> 7) & 3;
  int kb = (tid >> 9) & 31;
  int qt = (tid >> 14) & 15;
  int q = qt * 128 + w * 32 + (l & 31);
  int kbase = kb * 64 + kg * 32 + (l >> 5) * 4;
  const float* src = bias + (size_t)q * 2048 + kbase;
  u16x8 oa, ob;
#pragma unroll
  for (int rr = 0; rr < 4; ++rr) {
    float4 g = *(const float4*)(src + rr * 8);
    unsigned short e0 = f2bf(g.x * LOG2E), e1 = f2bf(g.y * LOG2E);
    unsigned short e2 = f2bf(g.z * LOG2E), e3 = f2bf(g.w * LOG2E);
    if (rr < 2) {
      oa[rr * 4 + 0] = e0; oa[rr * 4 + 1] = e1; oa[rr * 4 + 2] = e2; oa[rr * 4 + 3] = e3;
    } else {
      ob[(rr - 2) * 4 + 0] = e0; ob[(rr - 2) * 4 + 1] = e1;
      ob[(rr - 2) * 4 + 2] = e2; ob[(rr - 2) * 4 + 3] = e3;
    }
  }
  int base = (((qt * 32 + kb) * 4 + w) * 4 + kg * 2) * 64 + l;
  ((u16x8*)biasArr)[base] = oa;
  ((u16x8*)biasArr)[base + 64] = ob;
}

// ---------------- GEMM NT 128x128: out[m][n] = sum_k A[m][k]*B[n][k] ----------------
template <bool F32OUT>
__global__ __launch_bounds__(256) void gemm_nt(const unsigned short* __restrict__ A,
                                               const unsigned short* __restrict__ B,
                                               void* __restrict__ Cout,
                                               const float* __restrict__ bias,
                                               int M, int N, int K) {
  __shared__ __align__(16) unsigned short a_lds[128 * 64];
  __shared__ __align__(16) unsigned short b_lds[128 * 64];
  const int t = threadIdx.x;
  const int lane = t & 63, w = t >> 6;
  const int wm = w >> 1, wn = w & 1;
  const int r16 = lane >> 4, c16 = lane & 15;
  const int m0 = blockIdx.y * 128, n0 = blockIdx.x * 128;
  f32x4 acc[4][4] = {};
  for (int k0 = 0; k0 < K; k0 += 64) {
#pragma unroll
    for (int i = 0; i < 4; ++i) {
      int s = i * 256 + t;
      int row = s >> 3, c = s & 7;
      int cs = c ^ (row & 7);
      gload_lds16(A + (size_t)(m0 + row) * K + k0 + cs * 8, (char*)a_lds + s * 16);
      gload_lds16(B + (size_t)(n0 + row) * K + k0 + cs * 8, (char*)b_lds + s * 16);
    }
    __syncthreads();
#pragma unroll
    for (int ks = 0; ks < 2; ++ks) {
      bf16x8 af[4], bfr[4];
#pragma unroll
      for (int mi = 0; mi < 4; ++mi) {
        int row = wm * 64 + mi * 16 + c16;
        int ch = (r16 + ks * 4) ^ (row & 7);
        af[mi] = *(const bf16x8*)&a_lds[row * 64 + ch * 8];
      }
#pragma unroll
      for (int ni = 0; ni < 4; ++ni) {
        int row = wn * 64 + ni * 16 + c16;
        int ch = (r16 + ks * 4) ^ (row & 7);
        bfr[ni] = *(const bf16x8*)&b_lds[row * 64 + ch * 8];
      }
#pragma unroll
      for (int mi = 0; mi < 4; ++mi)
#pragma unroll
        for (int ni = 0; ni < 4; ++ni)
          acc[mi][ni] = __builtin_amdgcn_mfma_f32_16x16x32_bf16(af[mi], bfr[ni], acc[mi][ni], 0, 0, 0);
    }
    __syncthreads();
  }
#pragma unroll
  for (int mi = 0; mi < 4; ++mi)
#pragma unroll
    for (int ni = 0; ni < 4; ++ni)
#pragma unroll
      for (int r = 0; r < 4; ++r) {
        int m = m0 + wm * 64 + mi * 16 + r16 * 4 + r;
        int n = n0 + wn * 64 + ni * 16 + c16;
        float v = acc[mi][ni][r];
        if constexpr (F32OUT) {
          ((float*)Cout)[(size_t)m * N + n] = v + bias[n];
        } else {
          ((unsigned short*)Cout)[(size_t)m * N + n] = f2bf(v);
        }
      }
}

// ---------------- GEMM NT 128x64 tile (for small-N proj: 2 blocks/CU) ----------------
template <bool F32OUT>
__global__ __launch_bounds__(256) void gemm_nt64(const unsigned short* __restrict__ A,
                                                 const unsigned short* __restrict__ B,
                                                 void* __restrict__ Cout,
                                                 const float* __restrict__ bias,
                                                 int M, int N, int K) {
  __shared__ __align__(16) unsigned short a_lds[128 * 64];
  __shared__ __align__(16) unsigned short b_lds[64 * 64];
  const int t = threadIdx.x;
  const int lane = t & 63, w = t >> 6;
  const int wm = w >> 1, wn = w & 1;
  const int r16 = lane >> 4, c16 = lane & 15;
  const int m0 = blockIdx.y * 128, n0 = blockIdx.x * 64;
  f32x4 acc[4][2] = {};
  for (int k0 = 0; k0 < K; k0 += 64) {
#pragma unroll
    for (int i = 0; i < 4; ++i) {
      int s = i * 256 + t;
      int row = s >> 3, c = s & 7;
      int cs = c ^ (row & 7);
      gload_lds16(A + (size_t)(m0 + row) * K + k0 + cs * 8, (char*)a_lds + s * 16);
    }
#pragma unroll
    for (int i = 0; i < 2; ++i) {
      int s = i * 256 + t;
      int row = s >> 3, c = s & 7;
      int cs = c ^ (row & 7);
      gload_lds16(B + (size_t)(n0 + row) * K + k0 + cs * 8, (char*)b_lds + s * 16);
    }
    __syncthreads();
#pragma unroll
    for (int ks = 0; ks < 2; ++ks) {
      bf16x8 af[4], bfr[2];
#pragma unroll
      for (int mi = 0; mi < 4; ++mi) {
        int row = wm * 64 + mi * 16 + c16;
        int ch = (r16 + ks * 4) ^ (row & 7);
        af[mi] = *(const bf16x8*)&a_lds[row * 64 + ch * 8];
      }
#pragma unroll
      for (int ni = 0; ni < 2; ++ni) {
        int row = wn * 32 + ni * 16 + c16;
        int ch = (r16 + ks * 4) ^ (row & 7);
        bfr[ni] = *(const bf16x8*)&b_lds[row * 64 + ch * 8];
      }
#pragma unroll
      for (int mi = 0; mi < 4; ++mi)
#pragma unroll
        for (int ni = 0; ni < 2; ++ni)
          acc[mi][ni] = __builtin_amdgcn_mfma_f32_16x16x32_bf16(af[mi], bfr[ni], acc[mi][ni], 0, 0, 0);
    }
    __syncthreads();
  }
#pragma unroll
  for (int mi = 0; mi < 4; ++mi)
#pragma unroll
    for (int ni = 0; ni < 2; ++ni)
#pragma unroll
      for (int r = 0; r < 4; ++r) {
        int m = m0 + wm * 64 + mi * 16 + r16 * 4 + r;
        int n = n0 + wn * 32 + ni * 16 + c16;
        float v = acc[mi][ni][r];
        if constexpr (F32OUT) {
          ((float*)Cout)[(size_t)m * N + n] = v + bias[n];
        } else {
          ((unsigned short*)Cout)[(size_t)m * N + n] = f2bf(v);
        }
      }
}

// ---------------- normalize + bias + pack q,k,(v transposed) ----------------
__global__ __launch_bounds__(256) void norm_pack(const unsigned short* __restrict__ pre,
                                                 const float* __restrict__ q_bias,
                                                 const float* __restrict__ v_bias,
                                                 const float* __restrict__ scale_mul,
                                                 unsigned short* __restrict__ qo,
                                                 unsigned short* __restrict__ ko,
                                                 unsigned short* __restrict__ vto) {
  __shared__ float tl[64][65];
  const int t = threadIdx.x;
  const int li = t >> 2, dq = t & 3;
  const int tile = blockIdx.x;  // b*32 + lt
  const int sl = blockIdx.y;    // qkv*16 + h
  const int qkv = sl >> 4, h = sl & 15;
  const int b = tile >> 5, lt = tile & 31;
  const int l = lt * 64 + li;
  const int dbase = dq * 16;
  const unsigned short* src = pre + ((size_t)b * 2048 + l) * 3072 + qkv * 1024 + h * 64 + dbase;
  float v[16];
  bf16x8 x0 = *(const bf16x8*)src;
  bf16x8 x1 = *(const bf16x8*)(src + 8);
#pragma unroll
  for (int j = 0; j < 8; ++j) {
    v[j] = bf2f((unsigned short)x0[j]);
    v[8 + j] = bf2f((unsigned short)x1[j]);
  }
  if (qkv == 0) {
#pragma unroll
    for (int j = 0; j < 16; ++j) v[j] += q_bias[h * 64 + dbase + j];
  } else if (qkv == 2) {
#pragma unroll
    for (int j = 0; j < 16; ++j) v[j] += v_bias[h * 64 + dbase + j];
  }
  if (qkv < 2) {
    float ss = 0.f;
#pragma unroll
    for (int j = 0; j < 16; ++j) ss += v[j] * v[j];
    ss += __shfl_xor(ss, 1);
    ss += __shfl_xor(ss, 2);
    float inv = 1.0f / fmaxf(sqrtf(ss), 1e-12f);
    if (qkv == 0) inv *= __expf(fminf(scale_mul[h], 4.6051701859880914f));
    u16x8 o0, o1;
#pragma unroll
    for (int j = 0; j < 8; ++j) {
      o0[j] = f2bf(v[j] * inv);
      o1[j] = f2bf(v[8 + j] * inv);
    }
    unsigned short* dst = (qkv == 0 ? qo : ko) + ((size_t)(b * 16 + h) * 2048 + l) * 64 + dbase;
    *(u16x8*)dst = o0;
    *(u16x8*)(dst + 8) = o1;
  } else {
#pragma unroll
    for (int j = 0; j < 16; ++j) tl[li][dbase + j] = v[j];
    __syncthreads();
    const int d = li;
    const int lb = dq * 16;
    u16x8 o0, o1;
#pragma unroll
    for (int j = 0; j < 8; ++j) {
      o0[j] = f2bf(tl[lb + j][d]);
      o1[j] = f2bf(tl[lb + 8 + j][d]);
    }
    unsigned short* dst = vto + ((size_t)(b * 16 + h) * 64 + d) * 2048 + lt * 64 + lb;
    *(u16x8*)dst = o0;
    *(u16x8*)(dst + 8) = o1;
  }
}

// ---------------- flash attention: 32x32 MFMA, in-reg P, double-buffered DMA ----------------
// R9 inner iteration, but K/V/bias LDS are double-buffered and the stage for
// tile i+1 is issued AFTER the top-of-iter barrier (which drains loads issued a
// full compute phase earlier -> DMA latency off the critical path). 4 waves x
// 32 q-rows, grid 512, LDS 64 KB (2 blocks/CU).
__global__ __launch_bounds__(256) void attn_fwd(const unsigned short* __restrict__ qb,
                                                const unsigned short* __restrict__ kbuf,
                                                const unsigned short* __restrict__ vtb,
                                                const unsigned short* __restrict__ biasArr,
                                                unsigned short* __restrict__ oup) {
  __shared__ __align__(16) unsigned short k_lds[2][4096];   // 2 x  8 KB
  __shared__ __align__(16) unsigned short vt_lds[2][4096];  // 2 x  8 KB
  __shared__ __align__(16) unsigned short b_lds[2][8192];   // 2 x 16 KB
  const int t = threadIdx.x;
  const int lane = t & 63, w = t >> 6;
  const int l31 = lane & 31, hi = lane >> 5;
  const int bid = blockIdx.x;
  const int swz = (bid & 7) * 64 + (bid >> 3);
  const int bh = swz >> 4;
  const int qt = swz & 15;
  const int q0 = qt * 128;
  const int h = bh & 15;
  const size_t base = (size_t)bh * 2048 * 64;
  // staging sources (pre-permuted global, linear LDS dest)
  const unsigned short* kp = kbuf + base + (size_t)(t & 31) * 64 +
                             ((t >> 6) & 3) * 16 + ((t >> 5) & 1) * 8;
  const unsigned short* vp = vtb + base + (size_t)(t & 31) * 2048 +
                             ((t >> 6) & 3) * 16 + ((t >> 5) & 1) * 8;
  const unsigned short* bsrc = biasArr + (size_t)qt * 262144 + t * 8;
  // Q fragments (B-operand)
  bf16x8 qf[4];
  {
    const unsigned short* qp = qb + base + (size_t)(q0 + w * 32 + l31) * 64 + hi * 8;
    qf[0] = *(const bf16x8*)qp;
    qf[1] = *(const bf16x8*)(qp + 16);
    qf[2] = *(const bf16x8*)(qp + 32);
    qf[3] = *(const bf16x8*)(qp + 48);
  }
  f32x16 o0 = {}, o1 = {};
  float ls0 = 0.f, ls1 = 0.f;

  // prologue: stage tile 0 into buffer 0
  gload_lds16(kp, (char*)k_lds[0] + t * 16);
  gload_lds16(kp + 2048, (char*)k_lds[0] + t * 16 + 4096);
  gload_lds16(vp, (char*)vt_lds[0] + t * 16);
  gload_lds16(vp + 32 * 2048, (char*)vt_lds[0] + t * 16 + 4096);
#pragma unroll
  for (int i = 0; i < 4; ++i)
    gload_lds16(bsrc + i * 2048, (char*)b_lds[0] + t * 16 + i * 4096);

  for (int kb = 0; kb < 32; ++kb) {
    const int cur = kb & 1;
    __syncthreads();  // drains DMA issued one full compute phase ago
    // stage tile kb+1 into the other buffer (lands during this compute)
    if (kb + 1 < 32) {
      const int nxt = cur ^ 1;
      gload_lds16(kp + (size_t)(kb + 1) * 4096, (char*)k_lds[nxt] + t * 16);
      gload_lds16(kp + (size_t)(kb + 1) * 4096 + 2048, (char*)k_lds[nxt] + t * 16 + 4096);
      gload_lds16(vp + (kb + 1) * 64, (char*)vt_lds[nxt] + t * 16);
      gload_lds16(vp + (kb + 1) * 64 + 32 * 2048, (char*)vt_lds[nxt] + t * 16 + 4096);
#pragma unroll
      for (int i = 0; i < 4; ++i)
        gload_lds16(bsrc + (kb + 1) * 8192 + i * 2048, (char*)b_lds[nxt] + t * 16 + i * 4096);
    }
    // S^T = K Q^T : s0 = k-rows 0..31, s1 = 32..63 (col q = lane&31)
    f32x16 s0 = {}, s1 = {};
    __builtin_amdgcn_s_setprio(1);
#pragma unroll
    for (int dc = 0; dc < 4; ++dc) {
      bf16x8 kf0 = *(const bf16x8*)&k_lds[cur][dc * 512 + lane * 8];
      bf16x8 kf1 = *(const bf16x8*)&k_lds[cur][(4 + dc) * 512 + lane * 8];
      s0 = __builtin_amdgcn_mfma_f32_32x32x16_bf16(kf0, qf[dc], s0, 0, 0, 0);
      s1 = __builtin_amdgcn_mfma_f32_32x32x16_bf16(kf1, qf[dc], s1, 0, 0, 0);
    }
    __builtin_amdgcn_s_setprio(0);
    // bias from LDS, p = exp2(S*log2e + bias')
    const unsigned short* bl = b_lds[cur] + w * 2048 + lane * 8;
    bf16x8 b0 = *(const bf16x8*)(bl);
    bf16x8 b1 = *(const bf16x8*)(bl + 512);
    bf16x8 b2 = *(const bf16x8*)(bl + 1024);
    bf16x8 b3 = *(const bf16x8*)(bl + 1536);
    float p0[16], p1[16];
#pragma unroll
    for (int r = 0; r < 8; ++r) {
      p0[r] = __builtin_amdgcn_exp2f(__builtin_fmaf(s0[r], LOG2E, bf2f((unsigned short)b0[r])));
      p0[8 + r] = __builtin_amdgcn_exp2f(__builtin_fmaf(s0[8 + r], LOG2E, bf2f((unsigned short)b1[r])));
      p1[r] = __builtin_amdgcn_exp2f(__builtin_fmaf(s1[r], LOG2E, bf2f((unsigned short)b2[r])));
      p1[8 + r] = __builtin_amdgcn_exp2f(__builtin_fmaf(s1[8 + r], LOG2E, bf2f((unsigned short)b3[r])));
    }
#pragma unroll
    for (int r = 0; r < 16; ++r) { ls0 += p0[r]; ls1 += p1[r]; }
    // P -> PV B-frags in-register (cvt_pk + permlane32_swap)
    unsigned int x0 = cvt_pk_bf16(p0[0], p0[1]), x1 = cvt_pk_bf16(p0[2], p0[3]);
    unsigned int y0 = cvt_pk_bf16(p0[4], p0[5]), y1 = cvt_pk_bf16(p0[6], p0[7]);
    unsigned int z0 = cvt_pk_bf16(p0[8], p0[9]), z1 = cvt_pk_bf16(p0[10], p0[11]);
    unsigned int w0 = cvt_pk_bf16(p0[12], p0[13]), w1 = cvt_pk_bf16(p0[14], p0[15]);
    perm_swap(x0, y0); perm_swap(x1, y1); perm_swap(z0, w0); perm_swap(z1, w1);
    bf16x8 pf0 = mk8(x0, x1, y0, y1);
    bf16x8 pf1 = mk8(z0, z1, w0, w1);
    unsigned int a0 = cvt_pk_bf16(p1[0], p1[1]), a1 = cvt_pk_bf16(p1[2], p1[3]);
    unsigned int c0 = cvt_pk_bf16(p1[4], p1[5]), c1 = cvt_pk_bf16(p1[6], p1[7]);
    unsigned int d0 = cvt_pk_bf16(p1[8], p1[9]), d1 = cvt_pk_bf16(p1[10], p1[11]);
    unsigned int e0 = cvt_pk_bf16(p1[12], p1[13]), e1 = cvt_pk_bf16(p1[14], p1[15]);
    perm_swap(a0, c0); perm_swap(a1, c1); perm_swap(d0, e0); perm_swap(d1, e1);
    bf16x8 pf2 = mk8(a0, a1, c0, c1);
    bf16x8 pf3 = mk8(d0, d1, e0, e1);
    // O^T += V^T P^T
    bf16x8 pf[4] = {pf0, pf1, pf2, pf3};
    __builtin_amdgcn_s_setprio(1);
#pragma unroll
    for (int kc = 0; kc < 4; ++kc) {
      bf16x8 vf0 = *(const bf16x8*)&vt_lds[cur][kc * 512 + lane * 8];
      bf16x8 vf1 = *(const bf16x8*)&vt_lds[cur][(4 + kc) * 512 + lane * 8];
      o0 = __builtin_amdgcn_mfma_f32_32x32x16_bf16(vf0, pf[kc], o0, 0, 0, 0);
      o1 = __builtin_amdgcn_mfma_f32_32x32x16_bf16(vf1, pf[kc], o1, 0, 0, 0);
    }
    __builtin_amdgcn_s_setprio(0);
  }
  // epilogue
  float lsum = ls0 + ls1;
  lsum += __shfl_xor(lsum, 32);
  float inv = 1.0f / lsum;
  const int b = bh >> 4;
  unsigned short* orow = oup + ((size_t)b * 2048 + q0 + w * 32 + l31) * 1024 + h * 64;
#pragma unroll
  for (int dg = 0; dg < 2; ++dg) {
#pragma unroll
    for (int rr = 0; rr < 4; ++rr) {
      float v0 = (dg ? o1[rr * 4 + 0] : o0[rr * 4 + 0]) * inv;
      float v1 = (dg ? o1[rr * 4 + 1] : o0[rr * 4 + 1]) * inv;
      float v2 = (dg ? o1[rr * 4 + 2] : o0[rr * 4 + 2]) * inv;
      float v3 = (dg ? o1[rr * 4 + 3] : o0[rr * 4 + 3]) * inv;
      u32x2 pk2;
      pk2[0] = cvt_pk_bf16(v0, v1);
      pk2[1] = cvt_pk_bf16(v2, v3);
      int d = dg * 32 + rr * 8 + hi * 4;
      *(u32x2*)(orow + d) = pk2;
    }
  }
}

extern "C" void kernel_launch(void* const* d_in, const int* in_sizes, int n_in,
                              void* d_out, int out_size, void* d_ws, size_t ws_size,
                              hipStream_t stream) {
  const float* x = (const float*)d_in[0];
  const float* attn_bias = (const float*)d_in[1];
  const float* W_qkv = (const float*)d_in[2];
  const float* q_bias = (const float*)d_in[3];
  const float* v_bias = (const float*)d_in[4];
  const float* scale_mul = (const float*)d_in[5];
  const float* W_proj = (const float*)d_in[6];
  const float* b_proj = (const float*)d_in[7];
  float* out = (float*)d_out;
  char* ws = (char*)d_ws;

  unsigned short* x_bf = (unsigned short*)(ws + 0);            //  8 MB
  unsigned short* wqkv_bf = (unsigned short*)(ws + 8388608);   //  6 MB
  unsigned short* wproj_bf = (unsigned short*)(ws + 14680064); //  2 MB
  unsigned short* biasArr = (unsigned short*)(ws + 16777216);  //  8 MB (DMA-ordered, *log2e)
  unsigned short* q_pk = (unsigned short*)(ws + 25165824);     //  8 MB
  unsigned short* k_pk = (unsigned short*)(ws + 33554432);     //  8 MB
  unsigned short* vt_pk = (unsigned short*)(ws + 41943040);    //  8 MB
  unsigned short* oup_bf = (unsigned short*)(ws + 50331648);   //  8 MB
  unsigned short* pre_qkv = (unsigned short*)(ws + 58720256);  // 24 MB

  cvt_all<<<4096, 256, 0, stream>>>(x, W_qkv, W_proj, x_bf, wqkv_bf, wproj_bf);
  prep_bias<<<1024, 256, 0, stream>>>(attn_bias, biasArr);
  gemm_nt<false><<<dim3(24, 32), 256, 0, stream>>>(x_bf, wqkv_bf, (void*)pre_qkv, nullptr,
                                                   4096, 3072, 1024);
  norm_pack<<<dim3(64, 48), 256, 0, stream>>>(pre_qkv, q_bias, v_bias, scale_mul,
                                              q_pk, k_pk, vt_pk);
  attn_fwd<<<512, 256, 0, stream>>>(q_pk, k_pk, vt_pk, biasArr, oup_bf);
  gemm_nt64<true><<<dim3(16, 32), 256, 0, stream>>>(oup_bf, wproj_bf, (void*)out, b_proj,
                                                    4096, 1024, 1024);
}

// Round 12
// 135.371 us; speedup vs baseline: 1.2838x; 1.1266x over previous
//
#include <hip/hip_runtime.h>

typedef short bf16x8 __attribute__((ext_vector_type(8)));
typedef unsigned short u16x8 __attribute__((ext_vector_type(8)));
typedef float f32x4 __attribute__((ext_vector_type(4)));
typedef float f32x16 __attribute__((ext_vector_type(16)));
typedef unsigned int u32x2 __attribute__((ext_vector_type(2)));

#define LOG2E 1.44269504088896340736f

__device__ __forceinline__ float bf2f(unsigned short u) {
  union { unsigned int i; float f; } v; v.i = ((unsigned int)u) << 16; return v.f;
}
__device__ __forceinline__ unsigned short f2bf(float f) {
  union { float fl; unsigned int i; } v; v.fl = f;
  unsigned int r = v.i + 0x7FFFu + ((v.i >> 16) & 1u);
  return (unsigned short)(r >> 16);
}
__device__ __forceinline__ unsigned int cvt_pk_bf16(float lo, float hi) {
  unsigned int d;
  asm("v_cvt_pk_bf16_f32 %0, %1, %2" : "=v"(d) : "v"(lo), "v"(hi));
  return d;
}
__device__ __forceinline__ void perm_swap(unsigned int& a, unsigned int& b) {
  asm("v_permlane32_swap_b32 %0, %1" : "+v"(a), "+v"(b));
}
__device__ __forceinline__ bf16x8 mk8(unsigned int a, unsigned int b,
                                      unsigned int c, unsigned int d) {
  union { unsigned int u[4]; bf16x8 v; } r;
  r.u[0] = a; r.u[1] = b; r.u[2] = c; r.u[3] = d;
  return r.v;
}
__device__ __forceinline__ void gload_lds16(const void* g, void* l) {
  __builtin_amdgcn_global_load_lds(
      (const __attribute__((address_space(1))) void*)g,
      (__attribute__((address_space(3))) void*)l, 16, 0, 0);
}

// ---------------- fused fp32 -> bf16 conversions (x, W_qkv, W_proj) ----------------
__global__ __launch_bounds__(256) void cvt_all(const float* __restrict__ x,
                                               const float* __restrict__ wqkv,
                                               const float* __restrict__ wproj,
                                               unsigned short* __restrict__ xb,
                                               unsigned short* __restrict__ wqb,
                                               unsigned short* __restrict__ wpb) {
  int i = blockIdx.x * 256 + threadIdx.x;  // 1,048,576 total (x8 units)
  const float* src; unsigned short* dst; int off;
  if (i < 524288)       { src = x;     dst = xb;  off = i; }
  else if (i < 917504)  { src = wqkv;  dst = wqb; off = i - 524288; }
  else                  { src = wproj; dst = wpb; off = i - 917504; }
  float4 a = ((const float4*)src)[2 * off];
  float4 b = ((const float4*)src)[2 * off + 1];
  u16x8 o;
  o[0] = f2bf(a.x); o[1] = f2bf(a.y); o[2] = f2bf(a.z); o[3] = f2bf(a.w);
  o[4] = f2bf(b.x); o[5] = f2bf(b.y); o[6] = f2bf(b.z); o[7] = f2bf(b.w);
  ((u16x8*)dst)[off] = o;
}

// ---------------- bias -> frag-linear DMA-ordered layout ----------------
__global__ __launch_bounds__(256) void prep_bias(const float* __restrict__ bias,
                                                 unsigned short* __restrict__ biasArr) {
  int tid = blockIdx.x * 256 + threadIdx.x;  // 262,144 = (qt,kb,w,l,kg)
  int kg = tid & 1;
  int l = (tid >> 1) & 63;
  int w = (tid >> 7) & 3;
  int kb = (tid >> 9) & 31;
  int qt = (tid >> 14) & 15;
  int q = qt * 128 + w * 32 + (l & 31);
  int kbase = kb * 64 + kg * 32 + (l >> 5) * 4;
  const float* src = bias + (size_t)q * 2048 + kbase;
  u16x8 oa, ob;
#pragma unroll
  for (int rr = 0; rr < 4; ++rr) {
    float4 g = *(const float4*)(src + rr * 8);
    unsigned short e0 = f2bf(g.x * LOG2E), e1 = f2bf(g.y * LOG2E);
    unsigned short e2 = f2bf(g.z * LOG2E), e3 = f2bf(g.w * LOG2E);
    if (rr < 2) {
      oa[rr * 4 + 0] = e0; oa[rr * 4 + 1] = e1; oa[rr * 4 + 2] = e2; oa[rr * 4 + 3] = e3;
    } else {
      ob[(rr - 2) * 4 + 0] = e0; ob[(rr - 2) * 4 + 1] = e1;
      ob[(rr - 2) * 4 + 2] = e2; ob[(rr - 2) * 4 + 3] = e3;
    }
  }
  int base = (((qt * 32 + kb) * 4 + w) * 4 + kg * 2) * 64 + l;
  ((u16x8*)biasArr)[base] = oa;
  ((u16x8*)biasArr)[base + 64] = ob;
}

// ---------------- GEMM NT 128x128: out[m][n] = sum_k A[m][k]*B[n][k] ----------------
template <bool F32OUT>
__global__ __launch_bounds__(256) void gemm_nt(const unsigned short* __restrict__ A,
                                               const unsigned short* __restrict__ B,
                                               void* __restrict__ Cout,
                                               const float* __restrict__ bias,
                                               int M, int N, int K) {
  __shared__ __align__(16) unsigned short a_lds[128 * 64];
  __shared__ __align__(16) unsigned short b_lds[128 * 64];
  const int t = threadIdx.x;
  const int lane = t & 63, w = t >> 6;
  const int wm = w >> 1, wn = w & 1;
  const int r16 = lane >> 4, c16 = lane & 15;
  const int m0 = blockIdx.y * 128, n0 = blockIdx.x * 128;
  f32x4 acc[4][4] = {};
  for (int k0 = 0; k0 < K; k0 += 64) {
#pragma unroll
    for (int i = 0; i < 4; ++i) {
      int s = i * 256 + t;
      int row = s >> 3, c = s & 7;
      int cs = c ^ (row & 7);
      gload_lds16(A + (size_t)(m0 + row) * K + k0 + cs * 8, (char*)a_lds + s * 16);
      gload_lds16(B + (size_t)(n0 + row) * K + k0 + cs * 8, (char*)b_lds + s * 16);
    }
    __syncthreads();
#pragma unroll
    for (int ks = 0; ks < 2; ++ks) {
      bf16x8 af[4], bfr[4];
#pragma unroll
      for (int mi = 0; mi < 4; ++mi) {
        int row = wm * 64 + mi * 16 + c16;
        int ch = (r16 + ks * 4) ^ (row & 7);
        af[mi] = *(const bf16x8*)&a_lds[row * 64 + ch * 8];
      }
#pragma unroll
      for (int ni = 0; ni < 4; ++ni) {
        int row = wn * 64 + ni * 16 + c16;
        int ch = (r16 + ks * 4) ^ (row & 7);
        bfr[ni] = *(const bf16x8*)&b_lds[row * 64 + ch * 8];
      }
#pragma unroll
      for (int mi = 0; mi < 4; ++mi)
#pragma unroll
        for (int ni = 0; ni < 4; ++ni)
          acc[mi][ni] = __builtin_amdgcn_mfma_f32_16x16x32_bf16(af[mi], bfr[ni], acc[mi][ni], 0, 0, 0);
    }
    __syncthreads();
  }
#pragma unroll
  for (int mi = 0; mi < 4; ++mi)
#pragma unroll
    for (int ni = 0; ni < 4; ++ni)
#pragma unroll
      for (int r = 0; r < 4; ++r) {
        int m = m0 + wm * 64 + mi * 16 + r16 * 4 + r;
        int n = n0 + wn * 64 + ni * 16 + c16;
        float v = acc[mi][ni][r];
        if constexpr (F32OUT) {
          ((float*)Cout)[(size_t)m * N + n] = v + bias[n];
        } else {
          ((unsigned short*)Cout)[(size_t)m * N + n] = f2bf(v);
        }
      }
}

// ---------------- GEMM NT 128x64 tile (for small-N proj: 2 blocks/CU) ----------------
template <bool F32OUT>
__global__ __launch_bounds__(256) void gemm_nt64(const unsigned short* __restrict__ A,
                                                 const unsigned short* __restrict__ B,
                                                 void* __restrict__ Cout,
                                                 const float* __restrict__ bias,
                                                 int M, int N, int K) {
  __shared__ __align__(16) unsigned short a_lds[128 * 64];
  __shared__ __align__(16) unsigned short b_lds[64 * 64];
  const int t = threadIdx.x;
  const int lane = t & 63, w = t >> 6;
  const int wm = w >> 1, wn = w & 1;
  const int r16 = lane >> 4, c16 = lane & 15;
  const int m0 = blockIdx.y * 128, n0 = blockIdx.x * 64;
  f32x4 acc[4][2] = {};
  for (int k0 = 0; k0 < K; k0 += 64) {
#pragma unroll
    for (int i = 0; i < 4; ++i) {
      int s = i * 256 + t;
      int row = s >> 3, c = s & 7;
      int cs = c ^ (row & 7);
      gload_lds16(A + (size_t)(m0 + row) * K + k0 + cs * 8, (char*)a_lds + s * 16);
    }
#pragma unroll
    for (int i = 0; i < 2; ++i) {
      int s = i * 256 + t;
      int row = s >> 3, c = s & 7;
      int cs = c ^ (row & 7);
      gload_lds16(B + (size_t)(n0 + row) * K + k0 + cs * 8, (char*)b_lds + s * 16);
    }
    __syncthreads();
#pragma unroll
    for (int ks = 0; ks < 2; ++ks) {
      bf16x8 af[4], bfr[2];
#pragma unroll
      for (int mi = 0; mi < 4; ++mi) {
        int row = wm * 64 + mi * 16 + c16;
        int ch = (r16 + ks * 4) ^ (row & 7);
        af[mi] = *(const bf16x8*)&a_lds[row * 64 + ch * 8];
      }
#pragma unroll
      for (int ni = 0; ni < 2; ++ni) {
        int row = wn * 32 + ni * 16 + c16;
        int ch = (r16 + ks * 4) ^ (row & 7);
        bfr[ni] = *(const bf16x8*)&b_lds[row * 64 + ch * 8];
      }
#pragma unroll
      for (int mi = 0; mi < 4; ++mi)
#pragma unroll
        for (int ni = 0; ni < 2; ++ni)
          acc[mi][ni] = __builtin_amdgcn_mfma_f32_16x16x32_bf16(af[mi], bfr[ni], acc[mi][ni], 0, 0, 0);
    }
    __syncthreads();
  }
#pragma unroll
  for (int mi = 0; mi < 4; ++mi)
#pragma unroll
    for (int ni = 0; ni < 2; ++ni)
#pragma unroll
      for (int r = 0; r < 4; ++r) {
        int m = m0 + wm * 64 + mi * 16 + r16 * 4 + r;
        int n = n0 + wn * 32 + ni * 16 + c16;
        float v = acc[mi][ni][r];
        if constexpr (F32OUT) {
          ((float*)Cout)[(size_t)m * N + n] = v + bias[n];
        } else {
          ((unsigned short*)Cout)[(size_t)m * N + n] = f2bf(v);
        }
      }
}

// ---------------- normalize + bias + pack q,k,(v transposed) ----------------
__global__ __launch_bounds__(256) void norm_pack(const unsigned short* __restrict__ pre,
                                                 const float* __restrict__ q_bias,
                                                 const float* __restrict__ v_bias,
                                                 const float* __restrict__ scale_mul,
                                                 unsigned short* __restrict__ qo,
                                                 unsigned short* __restrict__ ko,
                                                 unsigned short* __restrict__ vto) {
  __shared__ float tl[64][65];
  const int t = threadIdx.x;
  const int li = t >> 2, dq = t & 3;
  const int tile = blockIdx.x;  // b*32 + lt
  const int sl = blockIdx.y;    // qkv*16 + h
  const int qkv = sl >> 4, h = sl & 15;
  const int b = tile >> 5, lt = tile & 31;
  const int l = lt * 64 + li;
  const int dbase = dq * 16;
  const unsigned short* src = pre + ((size_t)b * 2048 + l) * 3072 + qkv * 1024 + h * 64 + dbase;
  float v[16];
  bf16x8 x0 = *(const bf16x8*)src;
  bf16x8 x1 = *(const bf16x8*)(src + 8);
#pragma unroll
  for (int j = 0; j < 8; ++j) {
    v[j] = bf2f((unsigned short)x0[j]);
    v[8 + j] = bf2f((unsigned short)x1[j]);
  }
  if (qkv == 0) {
#pragma unroll
    for (int j = 0; j < 16; ++j) v[j] += q_bias[h * 64 + dbase + j];
  } else if (qkv == 2) {
#pragma unroll
    for (int j = 0; j < 16; ++j) v[j] += v_bias[h * 64 + dbase + j];
  }
  if (qkv < 2) {
    float ss = 0.f;
#pragma unroll
    for (int j = 0; j < 16; ++j) ss += v[j] * v[j];
    ss += __shfl_xor(ss, 1);
    ss += __shfl_xor(ss, 2);
    float inv = 1.0f / fmaxf(sqrtf(ss), 1e-12f);
    if (qkv == 0) inv *= __expf(fminf(scale_mul[h], 4.6051701859880914f));
    u16x8 o0, o1;
#pragma unroll
    for (int j = 0; j < 8; ++j) {
      o0[j] = f2bf(v[j] * inv);
      o1[j] = f2bf(v[8 + j] * inv);
    }
    unsigned short* dst = (qkv == 0 ? qo : ko) + ((size_t)(b * 16 + h) * 2048 + l) * 64 + dbase;
    *(u16x8*)dst = o0;
    *(u16x8*)(dst + 8) = o1;
  } else {
#pragma unroll
    for (int j = 0; j < 16; ++j) tl[li][dbase + j] = v[j];
    __syncthreads();
    const int d = li;
    const int lb = dq * 16;
    u16x8 o0, o1;
#pragma unroll
    for (int j = 0; j < 8; ++j) {
      o0[j] = f2bf(tl[lb + j][d]);
      o1[j] = f2bf(tl[lb + 8 + j][d]);
    }
    unsigned short* dst = vto + ((size_t)(b * 16 + h) * 64 + d) * 2048 + lt * 64 + lb;
    *(u16x8*)dst = o0;
    *(u16x8*)(dst + 8) = o1;
  }
}

// ---------------- flash attention: in-block K-split x2, 4 waves/SIMD ----------------
// 8 waves/block (512 thr): waves 0-3 k in [0,1024), waves 4-7 k in [1024,2048),
// same 128 q-rows. Sequential k-half phases inside each tile keep live regs
// <=128/wave (launch_bounds(512,4)) so 2 blocks/CU = 16 waves/CU = 4 waves/SIMD.
// Fixed-shift softmax => partials additive; combine via SoA LDS (conflict-free).
__global__ __launch_bounds__(512, 4) void attn_fwd(const unsigned short* __restrict__ qb,
                                                   const unsigned short* __restrict__ kbuf,
                                                   const unsigned short* __restrict__ vtb,
                                                   const unsigned short* __restrict__ biasArr,
                                                   unsigned short* __restrict__ oup) {
  __shared__ __align__(16) unsigned short k_lds[2][4096];   // 2 x  8 KB
  __shared__ __align__(16) unsigned short vt_lds[2][4096];  // 2 x  8 KB
  __shared__ __align__(16) unsigned short b_lds[2][8192];   // 2 x 16 KB
  const int t = threadIdx.x;
  const int lane = t & 63, w = t >> 6;
  const int sp = w >> 2;       // K-split half
  const int wq = w & 3;        // q sub-block
  const int tt = t & 255;      // thread id within half
  const int l31 = lane & 31, hi = lane >> 5;
  const int bid = blockIdx.x;
  const int swz = (bid & 7) * 64 + (bid >> 3);
  const int bh = swz >> 4;
  const int qt = swz & 15;
  const int q0 = qt * 128;
  const int h = bh & 15;
  const size_t base = (size_t)bh * 2048 * 64;
  // staging sources (pre-permuted global, linear LDS dest), per half
  const unsigned short* kp = kbuf + base + (size_t)(tt & 31) * 64 +
                             ((tt >> 6) & 3) * 16 + ((tt >> 5) & 1) * 8;
  const unsigned short* vp = vtb + base + (size_t)(tt & 31) * 2048 +
                             ((tt >> 6) & 3) * 16 + ((tt >> 5) & 1) * 8;
  const unsigned short* bsrc = biasArr + (size_t)qt * 262144 + tt * 8;
  // Q fragments (B-operand); both halves load the same q-rows
  bf16x8 qf[4];
  {
    const unsigned short* qp = qb + base + (size_t)(q0 + wq * 32 + l31) * 64 + hi * 8;
    qf[0] = *(const bf16x8*)qp;
    qf[1] = *(const bf16x8*)(qp + 16);
    qf[2] = *(const bf16x8*)(qp + 32);
    qf[3] = *(const bf16x8*)(qp + 48);
  }
  f32x16 o0 = {}, o1 = {};
  float ls = 0.f;

  for (int kbl = 0; kbl < 16; ++kbl) {
    const int kb = sp * 16 + kbl;
    // stage K (2), V^T (2), bias (4) into this half's frag-linear LDS
    gload_lds16(kp + (size_t)kb * 4096, (char*)k_lds[sp] + tt * 16);
    gload_lds16(kp + (size_t)kb * 4096 + 2048, (char*)k_lds[sp] + tt * 16 + 4096);
    gload_lds16(vp + kb * 64, (char*)vt_lds[sp] + tt * 16);
    gload_lds16(vp + kb * 64 + 32 * 2048, (char*)vt_lds[sp] + tt * 16 + 4096);
#pragma unroll
    for (int i = 0; i < 4; ++i)
      gload_lds16(bsrc + kb * 8192 + i * 2048, (char*)b_lds[sp] + tt * 16 + i * 4096);
    __syncthreads();
    const unsigned short* bl = b_lds[sp] + wq * 2048 + lane * 8;
    // ---- two sequential k-half phases (kg = 0,1) keep live s/p at half size ----
#pragma unroll
    for (int kg = 0; kg < 2; ++kg) {
      f32x16 s = {};
      __builtin_amdgcn_s_setprio(1);
#pragma unroll
      for (int dc = 0; dc < 4; ++dc) {
        bf16x8 kf = *(const bf16x8*)&k_lds[sp][(kg * 4 + dc) * 512 + lane * 8];
        s = __builtin_amdgcn_mfma_f32_32x32x16_bf16(kf, qf[dc], s, 0, 0, 0);
      }
      __builtin_amdgcn_s_setprio(0);
      bf16x8 b0 = *(const bf16x8*)(bl + kg * 1024);
      bf16x8 b1 = *(const bf16x8*)(bl + kg * 1024 + 512);
      float p[16];
#pragma unroll
      for (int r = 0; r < 8; ++r) {
        p[r] = __builtin_amdgcn_exp2f(__builtin_fmaf(s[r], LOG2E, bf2f((unsigned short)b0[r])));
        p[8 + r] = __builtin_amdgcn_exp2f(__builtin_fmaf(s[8 + r], LOG2E, bf2f((unsigned short)b1[r])));
      }
#pragma unroll
      for (int r = 0; r < 16; ++r) ls += p[r];
      unsigned int x0 = cvt_pk_bf16(p[0], p[1]), x1 = cvt_pk_bf16(p[2], p[3]);
      unsigned int y0 = cvt_pk_bf16(p[4], p[5]), y1 = cvt_pk_bf16(p[6], p[7]);
      unsigned int z0 = cvt_pk_bf16(p[8], p[9]), z1 = cvt_pk_bf16(p[10], p[11]);
      unsigned int w0 = cvt_pk_bf16(p[12], p[13]), w1 = cvt_pk_bf16(p[14], p[15]);
      perm_swap(x0, y0); perm_swap(x1, y1); perm_swap(z0, w0); perm_swap(z1, w1);
      bf16x8 pfa = mk8(x0, x1, y0, y1);  // k-cols kg*32 +  0..15
      bf16x8 pfb = mk8(z0, z1, w0, w1);  // k-cols kg*32 + 16..31
      __builtin_amdgcn_s_setprio(1);
#pragma unroll
      for (int kc = 0; kc < 2; ++kc) {
        bf16x8 pfx = kc ? pfb : pfa;
        bf16x8 vf0 = *(const bf16x8*)&vt_lds[sp][(kg * 2 + kc) * 512 + lane * 8];
        bf16x8 vf1 = *(const bf16x8*)&vt_lds[sp][(4 + kg * 2 + kc) * 512 + lane * 8];
        o0 = __builtin_amdgcn_mfma_f32_32x32x16_bf16(vf0, pfx, o0, 0, 0, 0);
        o1 = __builtin_amdgcn_mfma_f32_32x32x16_bf16(vf1, pfx, o1, 0, 0, 0);
      }
      __builtin_amdgcn_s_setprio(0);
    }
    __syncthreads();
  }
  // ---- combine halves via SoA LDS (conflict-free), then normalize + write ----
  float* fO = (float*)b_lds;   // 32 KB: [i][slot]
  float* fL = (float*)k_lds;   //  1 KB: [slot]
  const int slot = wq * 64 + lane;  // 0..255
  if (sp == 1) {
#pragma unroll
    for (int i = 0; i < 16; ++i) {
      fO[i * 256 + slot] = o0[i];
      fO[(16 + i) * 256 + slot] = o1[i];
    }
    fL[slot] = ls;
  }
  __syncthreads();
  if (sp == 0) {
#pragma unroll
    for (int i = 0; i < 16; ++i) {
      o0[i] += fO[i * 256 + slot];
      o1[i] += fO[(16 + i) * 256 + slot];
    }
    ls += fL[slot];
    float lsum = ls + __shfl_xor(ls, 32);
    float inv = 1.0f / lsum;
    const int b = bh >> 4;
    unsigned short* orow = oup + ((size_t)b * 2048 + q0 + wq * 32 + l31) * 1024 + h * 64;
#pragma unroll
    for (int dg = 0; dg < 2; ++dg) {
#pragma unroll
      for (int rr = 0; rr < 4; ++rr) {
        float v0 = (dg ? o1[rr * 4 + 0] : o0[rr * 4 + 0]) * inv;
        float v1 = (dg ? o1[rr * 4 + 1] : o0[rr * 4 + 1]) * inv;
        float v2 = (dg ? o1[rr * 4 + 2] : o0[rr * 4 + 2]) * inv;
        float v3 = (dg ? o1[rr * 4 + 3] : o0[rr * 4 + 3]) * inv;
        u32x2 pk2;
        pk2[0] = cvt_pk_bf16(v0, v1);
        pk2[1] = cvt_pk_bf16(v2, v3);
        int d = dg * 32 + rr * 8 + hi * 4;
        *(u32x2*)(orow + d) = pk2;
      }
    }
  }
}

extern "C" void kernel_launch(void* const* d_in, const int* in_sizes, int n_in,
                              void* d_out, int out_size, void* d_ws, size_t ws_size,
                              hipStream_t stream) {
  const float* x = (const float*)d_in[0];
  const float* attn_bias = (const float*)d_in[1];
  const float* W_qkv = (const float*)d_in[2];
  const float* q_bias = (const float*)d_in[3];
  const float* v_bias = (const float*)d_in[4];
  const float* scale_mul = (const float*)d_in[5];
  const float* W_proj = (const float*)d_in[6];
  const float* b_proj = (const float*)d_in[7];
  float* out = (float*)d_out;
  char* ws = (char*)d_ws;

  unsigned short* x_bf = (unsigned short*)(ws + 0);            //  8 MB
  unsigned short* wqkv_bf = (unsigned short*)(ws + 8388608);   //  6 MB
  unsigned short* wproj_bf = (unsigned short*)(ws + 14680064); //  2 MB
  unsigned short* biasArr = (unsigned short*)(ws + 16777216);  //  8 MB (DMA-ordered, *log2e)
  unsigned short* q_pk = (unsigned short*)(ws + 25165824);     //  8 MB
  unsigned short* k_pk = (unsigned short*)(ws + 33554432);     //  8 MB
  unsigned short* vt_pk = (unsigned short*)(ws + 41943040);    //  8 MB
  unsigned short* oup_bf = (unsigned short*)(ws + 50331648);   //  8 MB
  unsigned short* pre_qkv = (unsigned short*)(ws + 58720256);  // 24 MB

  cvt_all<<<4096, 256, 0, stream>>>(x, W_qkv, W_proj, x_bf, wqkv_bf, wproj_bf);
  prep_bias<<<1024, 256, 0, stream>>>(attn_bias, biasArr);
  gemm_nt<false><<<dim3(24, 32), 256, 0, stream>>>(x_bf, wqkv_bf, (void*)pre_qkv, nullptr,
                                                   4096, 3072, 1024);
  norm_pack<<<dim3(64, 48), 256, 0, stream>>>(pre_qkv, q_bias, v_bias, scale_mul,
                                              q_pk, k_pk, vt_pk);
  attn_fwd<<<512, 512, 0, stream>>>(q_pk, k_pk, vt_pk, biasArr, oup_bf);
  gemm_nt64<true><<<dim3(16, 32), 256, 0, stream>>>(oup_bf, wproj_bf, (void*)out, b_proj,
                                                    4096, 1024, 1024);
}

// Round 13
// 133.693 us; speedup vs baseline: 1.3000x; 1.0126x over previous
//
#include <hip/hip_runtime.h>

typedef short bf16x8 __attribute__((ext_vector_type(8)));
typedef unsigned short u16x8 __attribute__((ext_vector_type(8)));
typedef unsigned short u16x4 __attribute__((ext_vector_type(4)));
typedef float f32x4 __attribute__((ext_vector_type(4)));
typedef float f32x16 __attribute__((ext_vector_type(16)));
typedef unsigned int u32x2 __attribute__((ext_vector_type(2)));

#define LOG2E 1.44269504088896340736f

__device__ __forceinline__ float bf2f(unsigned short u) {
  union { unsigned int i; float f; } v; v.i = ((unsigned int)u) << 16; return v.f;
}
__device__ __forceinline__ unsigned short f2bf(float f) {
  union { float fl; unsigned int i; } v; v.fl = f;
  unsigned int r = v.i + 0x7FFFu + ((v.i >> 16) & 1u);
  return (unsigned short)(r >> 16);
}
__device__ __forceinline__ unsigned int cvt_pk_bf16(float lo, float hi) {
  unsigned int d;
  asm("v_cvt_pk_bf16_f32 %0, %1, %2" : "=v"(d) : "v"(lo), "v"(hi));
  return d;
}
__device__ __forceinline__ void perm_swap(unsigned int& a, unsigned int& b) {
  asm("v_permlane32_swap_b32 %0, %1" : "+v"(a), "+v"(b));
}
__device__ __forceinline__ bf16x8 mk8(unsigned int a, unsigned int b,
                                      unsigned int c, unsigned int d) {
  union { unsigned int u[4]; bf16x8 v; } r;
  r.u[0] = a; r.u[1] = b; r.u[2] = c; r.u[3] = d;
  return r.v;
}
__device__ __forceinline__ void gload_lds16(const void* g, void* l) {
  __builtin_amdgcn_global_load_lds(
      (const __attribute__((address_space(1))) void*)g,
      (__attribute__((address_space(3))) void*)l, 16, 0, 0);
}

// ------- fused fp32->bf16 conversions (x, W_qkv, W_proj) + bias prep (one launch) -------
__global__ __launch_bounds__(256) void cvt_prep(const float* __restrict__ x,
                                                const float* __restrict__ wqkv,
                                                const float* __restrict__ wproj,
                                                const float* __restrict__ bias,
                                                unsigned short* __restrict__ xb,
                                                unsigned short* __restrict__ wqb,
                                                unsigned short* __restrict__ wpb,
                                                unsigned short* __restrict__ biasArr) {
  int i = blockIdx.x * 256 + threadIdx.x;  // 1,048,576 cvt units + 262,144 prep units
  if (i < 1048576) {
    const float* src; unsigned short* dst; int off;
    if (i < 524288)       { src = x;     dst = xb;  off = i; }
    else if (i < 917504)  { src = wqkv;  dst = wqb; off = i - 524288; }
    else                  { src = wproj; dst = wpb; off = i - 917504; }
    float4 a = ((const float4*)src)[2 * off];
    float4 b = ((const float4*)src)[2 * off + 1];
    u16x8 o;
    o[0] = f2bf(a.x); o[1] = f2bf(a.y); o[2] = f2bf(a.z); o[3] = f2bf(a.w);
    o[4] = f2bf(b.x); o[5] = f2bf(b.y); o[6] = f2bf(b.z); o[7] = f2bf(b.w);
    ((u16x8*)dst)[off] = o;
  } else {
    // bias -> frag-linear DMA-ordered layout (see R9 notes)
    int tid = i - 1048576;  // (qt,kb,w,l,kg)
    int kg = tid & 1;
    int l = (tid >> 1) & 63;
    int w = (tid >> 7) & 3;
    int kb = (tid >> 9) & 31;
    int qt = (tid >> 14) & 15;
    int q = qt * 128 + w * 32 + (l & 31);
    int kbase = kb * 64 + kg * 32 + (l >> 5) * 4;
    const float* src = bias + (size_t)q * 2048 + kbase;
    u16x8 oa, ob;
#pragma unroll
    for (int rr = 0; rr < 4; ++rr) {
      float4 g = *(const float4*)(src + rr * 8);
      unsigned short e0 = f2bf(g.x * LOG2E), e1 = f2bf(g.y * LOG2E);
      unsigned short e2 = f2bf(g.z * LOG2E), e3 = f2bf(g.w * LOG2E);
      if (rr < 2) {
        oa[rr * 4 + 0] = e0; oa[rr * 4 + 1] = e1; oa[rr * 4 + 2] = e2; oa[rr * 4 + 3] = e3;
      } else {
        ob[(rr - 2) * 4 + 0] = e0; ob[(rr - 2) * 4 + 1] = e1;
        ob[(rr - 2) * 4 + 2] = e2; ob[(rr - 2) * 4 + 3] = e3;
      }
    }
    int base = (((qt * 32 + kb) * 4 + w) * 4 + kg * 2) * 64 + l;
    ((u16x8*)biasArr)[base] = oa;
    ((u16x8*)biasArr)[base + 64] = ob;
  }
}

// ------- QKV GEMM with fused bias + l2norm + pack epilogue -------
// C = x_bf (4096x1024) . wqkv_bf^T (3072x1024). A 128-wide N-tile covers exactly
// 2 heads of one of q/k/v: tp = n0>>10, head h = (n0&1023)/64 + wn, d = ni*16+c16.
// q/k: row l2norm over d = per-lane sum over ni + shfl_xor(1,2,4,8) within the
// c16 group; q also scaled by exp(min(scale_mul[h],ln100)). v: bias add, then
// direct transposed write (u16x4 over r = 4 consecutive l at fixed d).
__global__ __launch_bounds__(256) void gemm_qkv(const unsigned short* __restrict__ A,
                                                const unsigned short* __restrict__ B,
                                                const float* __restrict__ q_bias,
                                                const float* __restrict__ v_bias,
                                                const float* __restrict__ scale_mul,
                                                unsigned short* __restrict__ qo,
                                                unsigned short* __restrict__ ko,
                                                unsigned short* __restrict__ vto) {
  __shared__ __align__(16) unsigned short a_lds[128 * 64];
  __shared__ __align__(16) unsigned short b_lds[128 * 64];
  const int t = threadIdx.x;
  const int lane = t & 63, w = t >> 6;
  const int wm = w >> 1, wn = w & 1;
  const int r16 = lane >> 4, c16 = lane & 15;
  const int m0 = blockIdx.y * 128, n0 = blockIdx.x * 128;
  f32x4 acc[4][4] = {};
  for (int k0 = 0; k0 < 1024; k0 += 64) {
#pragma unroll
    for (int i = 0; i < 4; ++i) {
      int s = i * 256 + t;
      int row = s >> 3, c = s & 7;
      int cs = c ^ (row & 7);
      gload_lds16(A + (size_t)(m0 + row) * 1024 + k0 + cs * 8, (char*)a_lds + s * 16);
      gload_lds16(B + (size_t)(n0 + row) * 1024 + k0 + cs * 8, (char*)b_lds + s * 16);
    }
    __syncthreads();
#pragma unroll
    for (int ks = 0; ks < 2; ++ks) {
      bf16x8 af[4], bfr[4];
#pragma unroll
      for (int mi = 0; mi < 4; ++mi) {
        int row = wm * 64 + mi * 16 + c16;
        int ch = (r16 + ks * 4) ^ (row & 7);
        af[mi] = *(const bf16x8*)&a_lds[row * 64 + ch * 8];
      }
#pragma unroll
      for (int ni = 0; ni < 4; ++ni) {
        int row = wn * 64 + ni * 16 + c16;
        int ch = (r16 + ks * 4) ^ (row & 7);
        bfr[ni] = *(const bf16x8*)&b_lds[row * 64 + ch * 8];
      }
#pragma unroll
      for (int mi = 0; mi < 4; ++mi)
#pragma unroll
        for (int ni = 0; ni < 4; ++ni)
          acc[mi][ni] = __builtin_amdgcn_mfma_f32_16x16x32_bf16(af[mi], bfr[ni], acc[mi][ni], 0, 0, 0);
    }
    __syncthreads();
  }
  // ---- fused epilogue ----
  const int tp = n0 >> 10;              // 0=q, 1=k, 2=v
  const int nq = n0 & 1023;
  const int h = (nq >> 6) + wn;         // head for this wave-column
  const int bb = (m0 >= 2048) ? 1 : 0;
  const int l0 = (m0 & 2047) + wm * 64; // + mi*16 + r16*4 + r
  if (tp == 2) {
    float bias_d[4];
#pragma unroll
    for (int ni = 0; ni < 4; ++ni) bias_d[ni] = v_bias[h * 64 + ni * 16 + c16];
    unsigned short* dstb = vto + (size_t)(bb * 16 + h) * 64 * 2048;
#pragma unroll
    for (int mi = 0; mi < 4; ++mi)
#pragma unroll
      for (int ni = 0; ni < 4; ++ni) {
        int d = ni * 16 + c16;
        u16x4 ov;
#pragma unroll
        for (int r = 0; r < 4; ++r) ov[r] = f2bf(acc[mi][ni][r] + bias_d[ni]);
        *(u16x4*)(dstb + (size_t)d * 2048 + l0 + mi * 16 + r16 * 4) = ov;
      }
  } else {
    float bias_d[4] = {0.f, 0.f, 0.f, 0.f};
    float qscale = 1.0f;
    if (tp == 0) {
#pragma unroll
      for (int ni = 0; ni < 4; ++ni) bias_d[ni] = q_bias[h * 64 + ni * 16 + c16];
      qscale = __expf(fminf(scale_mul[h], 4.6051701859880914f));
    }
    unsigned short* dst = (tp == 0 ? qo : ko) + (size_t)(bb * 16 + h) * 2048 * 64;
#pragma unroll
    for (int mi = 0; mi < 4; ++mi)
#pragma unroll
      for (int r = 0; r < 4; ++r) {
        float vv[4];
        float ss = 0.f;
#pragma unroll
        for (int ni = 0; ni < 4; ++ni) {
          vv[ni] = acc[mi][ni][r] + bias_d[ni];
          ss += vv[ni] * vv[ni];
        }
        ss += __shfl_xor(ss, 1);
        ss += __shfl_xor(ss, 2);
        ss += __shfl_xor(ss, 4);
        ss += __shfl_xor(ss, 8);
        float inv = qscale / fmaxf(sqrtf(ss), 1e-12f);
        int l = l0 + mi * 16 + r16 * 4 + r;
#pragma unroll
        for (int ni = 0; ni < 4; ++ni)
          dst[(size_t)l * 64 + ni * 16 + c16] = f2bf(vv[ni] * inv);
      }
  }
}

// ---------------- GEMM NT 128x64 tile (proj) ----------------
template <bool F32OUT>
__global__ __launch_bounds__(256) void gemm_nt64(const unsigned short* __restrict__ A,
                                                 const unsigned short* __restrict__ B,
                                                 void* __restrict__ Cout,
                                                 const float* __restrict__ bias,
                                                 int M, int N, int K) {
  __shared__ __align__(16) unsigned short a_lds[128 * 64];
  __shared__ __align__(16) unsigned short b_lds[64 * 64];
  const int t = threadIdx.x;
  const int lane = t & 63, w = t >> 6;
  const int wm = w >> 1, wn = w & 1;
  const int r16 = lane >> 4, c16 = lane & 15;
  const int m0 = blockIdx.y * 128, n0 = blockIdx.x * 64;
  f32x4 acc[4][2] = {};
  for (int k0 = 0; k0 < K; k0 += 64) {
#pragma unroll
    for (int i = 0; i < 4; ++i) {
      int s = i * 256 + t;
      int row = s >> 3, c = s & 7;
      int cs = c ^ (row & 7);
      gload_lds16(A + (size_t)(m0 + row) * K + k0 + cs * 8, (char*)a_lds + s * 16);
    }
#pragma unroll
    for (int i = 0; i < 2; ++i) {
      int s = i * 256 + t;
      int row = s >> 3, c = s & 7;
      int cs = c ^ (row & 7);
      gload_lds16(B + (size_t)(n0 + row) * K + k0 + cs * 8, (char*)b_lds + s * 16);
    }
    __syncthreads();
#pragma unroll
    for (int ks = 0; ks < 2; ++ks) {
      bf16x8 af[4], bfr[2];
#pragma unroll
      for (int mi = 0; mi < 4; ++mi) {
        int row = wm * 64 + mi * 16 + c16;
        int ch = (r16 + ks * 4) ^ (row & 7);
        af[mi] = *(const bf16x8*)&a_lds[row * 64 + ch * 8];
      }
#pragma unroll
      for (int ni = 0; ni < 2; ++ni) {
        int row = wn * 32 + ni * 16 + c16;
        int ch = (r16 + ks * 4) ^ (row & 7);
        bfr[ni] = *(const bf16x8*)&b_lds[row * 64 + ch * 8];
      }
#pragma unroll
      for (int mi = 0; mi < 4; ++mi)
#pragma unroll
        for (int ni = 0; ni < 2; ++ni)
          acc[mi][ni] = __builtin_amdgcn_mfma_f32_16x16x32_bf16(af[mi], bfr[ni], acc[mi][ni], 0, 0, 0);
    }
    __syncthreads();
  }
#pragma unroll
  for (int mi = 0; mi < 4; ++mi)
#pragma unroll
    for (int ni = 0; ni < 2; ++ni)
#pragma unroll
      for (int r = 0; r < 4; ++r) {
        int m = m0 + wm * 64 + mi * 16 + r16 * 4 + r;
        int n = n0 + wn * 32 + ni * 16 + c16;
        float v = acc[mi][ni][r];
        if constexpr (F32OUT) {
          ((float*)Cout)[(size_t)m * N + n] = v + bias[n];
        } else {
          ((unsigned short*)Cout)[(size_t)m * N + n] = f2bf(v);
        }
      }
}

// ---------------- flash attention: in-block K-split x2, 4 waves/SIMD (R12) ----------------
__global__ __launch_bounds__(512, 4) void attn_fwd(const unsigned short* __restrict__ qb,
                                                   const unsigned short* __restrict__ kbuf,
                                                   const unsigned short* __restrict__ vtb,
                                                   const unsigned short* __restrict__ biasArr,
                                                   unsigned short* __restrict__ oup) {
  __shared__ __align__(16) unsigned short k_lds[2][4096];   // 2 x  8 KB
  __shared__ __align__(16) unsigned short vt_lds[2][4096];  // 2 x  8 KB
  __shared__ __align__(16) unsigned short b_lds[2][8192];   // 2 x 16 KB
  const int t = threadIdx.x;
  const int lane = t & 63, w = t >> 6;
  const int sp = w >> 2;       // K-split half
  const int wq = w & 3;        // q sub-block
  const int tt = t & 255;      // thread id within half
  const int l31 = lane & 31, hi = lane >> 5;
  const int bid = blockIdx.x;
  const int swz = (bid & 7) * 64 + (bid >> 3);
  const int bh = swz >> 4;
  const int qt = swz & 15;
  const int q0 = qt * 128;
  const int h = bh & 15;
  const size_t base = (size_t)bh * 2048 * 64;
  const unsigned short* kp = kbuf + base + (size_t)(tt & 31) * 64 +
                             ((tt >> 6) & 3) * 16 + ((tt >> 5) & 1) * 8;
  const unsigned short* vp = vtb + base + (size_t)(tt & 31) * 2048 +
                             ((tt >> 6) & 3) * 16 + ((tt >> 5) & 1) * 8;
  const unsigned short* bsrc = biasArr + (size_t)qt * 262144 + tt * 8;
  bf16x8 qf[4];
  {
    const unsigned short* qp = qb + base + (size_t)(q0 + wq * 32 + l31) * 64 + hi * 8;
    qf[0] = *(const bf16x8*)qp;
    qf[1] = *(const bf16x8*)(qp + 16);
    qf[2] = *(const bf16x8*)(qp + 32);
    qf[3] = *(const bf16x8*)(qp + 48);
  }
  f32x16 o0 = {}, o1 = {};
  float ls = 0.f;

  for (int kbl = 0; kbl < 16; ++kbl) {
    const int kb = sp * 16 + kbl;
    gload_lds16(kp + (size_t)kb * 4096, (char*)k_lds[sp] + tt * 16);
    gload_lds16(kp + (size_t)kb * 4096 + 2048, (char*)k_lds[sp] + tt * 16 + 4096);
    gload_lds16(vp + kb * 64, (char*)vt_lds[sp] + tt * 16);
    gload_lds16(vp + kb * 64 + 32 * 2048, (char*)vt_lds[sp] + tt * 16 + 4096);
#pragma unroll
    for (int i = 0; i < 4; ++i)
      gload_lds16(bsrc + kb * 8192 + i * 2048, (char*)b_lds[sp] + tt * 16 + i * 4096);
    __syncthreads();
    const unsigned short* bl = b_lds[sp] + wq * 2048 + lane * 8;
#pragma unroll
    for (int kg = 0; kg < 2; ++kg) {
      f32x16 s = {};
      __builtin_amdgcn_s_setprio(1);
#pragma unroll
      for (int dc = 0; dc < 4; ++dc) {
        bf16x8 kf = *(const bf16x8*)&k_lds[sp][(kg * 4 + dc) * 512 + lane * 8];
        s = __builtin_amdgcn_mfma_f32_32x32x16_bf16(kf, qf[dc], s, 0, 0, 0);
      }
      __builtin_amdgcn_s_setprio(0);
      bf16x8 b0 = *(const bf16x8*)(bl + kg * 1024);
      bf16x8 b1 = *(const bf16x8*)(bl + kg * 1024 + 512);
      float p[16];
#pragma unroll
      for (int r = 0; r < 8; ++r) {
        p[r] = __builtin_amdgcn_exp2f(__builtin_fmaf(s[r], LOG2E, bf2f((unsigned short)b0[r])));
        p[8 + r] = __builtin_amdgcn_exp2f(__builtin_fmaf(s[8 + r], LOG2E, bf2f((unsigned short)b1[r])));
      }
#pragma unroll
      for (int r = 0; r < 16; ++r) ls += p[r];
      unsigned int x0 = cvt_pk_bf16(p[0], p[1]), x1 = cvt_pk_bf16(p[2], p[3]);
      unsigned int y0 = cvt_pk_bf16(p[4], p[5]), y1 = cvt_pk_bf16(p[6], p[7]);
      unsigned int z0 = cvt_pk_bf16(p[8], p[9]), z1 = cvt_pk_bf16(p[10], p[11]);
      unsigned int w0 = cvt_pk_bf16(p[12], p[13]), w1 = cvt_pk_bf16(p[14], p[15]);
      perm_swap(x0, y0); perm_swap(x1, y1); perm_swap(z0, w0); perm_swap(z1, w1);
      bf16x8 pfa = mk8(x0, x1, y0, y1);
      bf16x8 pfb = mk8(z0, z1, w0, w1);
      __builtin_amdgcn_s_setprio(1);
#pragma unroll
      for (int kc = 0; kc < 2; ++kc) {
        bf16x8 pfx = kc ? pfb : pfa;
        bf16x8 vf0 = *(const bf16x8*)&vt_lds[sp][(kg * 2 + kc) * 512 + lane * 8];
        bf16x8 vf1 = *(const bf16x8*)&vt_lds[sp][(4 + kg * 2 + kc) * 512 + lane * 8];
        o0 = __builtin_amdgcn_mfma_f32_32x32x16_bf16(vf0, pfx, o0, 0, 0, 0);
        o1 = __builtin_amdgcn_mfma_f32_32x32x16_bf16(vf1, pfx, o1, 0, 0, 0);
      }
      __builtin_amdgcn_s_setprio(0);
    }
    __syncthreads();
  }
  // combine halves via SoA LDS, then normalize + write
  float* fO = (float*)b_lds;
  float* fL = (float*)k_lds;
  const int slot = wq * 64 + lane;
  if (sp == 1) {
#pragma unroll
    for (int i = 0; i < 16; ++i) {
      fO[i * 256 + slot] = o0[i];
      fO[(16 + i) * 256 + slot] = o1[i];
    }
    fL[slot] = ls;
  }
  __syncthreads();
  if (sp == 0) {
#pragma unroll
    for (int i = 0; i < 16; ++i) {
      o0[i] += fO[i * 256 + slot];
      o1[i] += fO[(16 + i) * 256 + slot];
    }
    ls += fL[slot];
    float lsum = ls + __shfl_xor(ls, 32);
    float inv = 1.0f / lsum;
    const int b = bh >> 4;
    unsigned short* orow = oup + ((size_t)b * 2048 + q0 + wq * 32 + l31) * 1024 + h * 64;
#pragma unroll
    for (int dg = 0; dg < 2; ++dg) {
#pragma unroll
      for (int rr = 0; rr < 4; ++rr) {
        float v0 = (dg ? o1[rr * 4 + 0] : o0[rr * 4 + 0]) * inv;
        float v1 = (dg ? o1[rr * 4 + 1] : o0[rr * 4 + 1]) * inv;
        float v2 = (dg ? o1[rr * 4 + 2] : o0[rr * 4 + 2]) * inv;
        float v3 = (dg ? o1[rr * 4 + 3] : o0[rr * 4 + 3]) * inv;
        u32x2 pk2;
        pk2[0] = cvt_pk_bf16(v0, v1);
        pk2[1] = cvt_pk_bf16(v2, v3);
        int d = dg * 32 + rr * 8 + hi * 4;
        *(u32x2*)(orow + d) = pk2;
      }
    }
  }
}

extern "C" void kernel_launch(void* const* d_in, const int* in_sizes, int n_in,
                              void* d_out, int out_size, void* d_ws, size_t ws_size,
                              hipStream_t stream) {
  const float* x = (const float*)d_in[0];
  const float* attn_bias = (const float*)d_in[1];
  const float* W_qkv = (const float*)d_in[2];
  const float* q_bias = (const float*)d_in[3];
  const float* v_bias = (const float*)d_in[4];
  const float* scale_mul = (const float*)d_in[5];
  const float* W_proj = (const float*)d_in[6];
  const float* b_proj = (const float*)d_in[7];
  float* out = (float*)d_out;
  char* ws = (char*)d_ws;

  unsigned short* x_bf = (unsigned short*)(ws + 0);            //  8 MB
  unsigned short* wqkv_bf = (unsigned short*)(ws + 8388608);   //  6 MB
  unsigned short* wproj_bf = (unsigned short*)(ws + 14680064); //  2 MB
  unsigned short* biasArr = (unsigned short*)(ws + 16777216);  //  8 MB (DMA-ordered, *log2e)
  unsigned short* q_pk = (unsigned short*)(ws + 25165824);     //  8 MB
  unsigned short* k_pk = (unsigned short*)(ws + 33554432);     //  8 MB
  unsigned short* vt_pk = (unsigned short*)(ws + 41943040);    //  8 MB
  unsigned short* oup_bf = (unsigned short*)(ws + 50331648);   //  8 MB

  cvt_prep<<<5120, 256, 0, stream>>>(x, W_qkv, W_proj, attn_bias,
                                     x_bf, wqkv_bf, wproj_bf, biasArr);
  gemm_qkv<<<dim3(24, 32), 256, 0, stream>>>(x_bf, wqkv_bf, q_bias, v_bias, scale_mul,
                                             q_pk, k_pk, vt_pk);
  attn_fwd<<<512, 512, 0, stream>>>(q_pk, k_pk, vt_pk, biasArr, oup_bf);
  gemm_nt64<true><<<dim3(16, 32), 256, 0, stream>>>(oup_bf, wproj_bf, (void*)out, b_proj,
                                                    4096, 1024, 1024);
}